// Round 2
// baseline (184.833 us; speedup 1.0000x reference)
//
#include <hip/hip_runtime.h>

// MoGeSampledLocalLoss: per-patch truncated robust affine depth alignment +
// smooth-L1 loss, global mean over valid patches.
//
// R8: occupancy push to the 8-waves/SIMD tier. R7's coalescing remap was
// neutral -> transaction count was never the limiter. Remaining theory:
// latency/residency. At launch_bounds(256,4) + ~90-100 VGPRs only 4096 of
// the 8192 waves are resident (2 dispatch rounds, 4 waves/SIMD). R8 packs
// the 16 per-lane mask words into ONE 16-bit register right after load
// (frees 16 VGPRs; peak live ~60) and forces __launch_bounds__(256,8) so
// ALL waves are resident in a single round with 8 waves/SIMD hiding HBM
// latency. Math is bit-identical (mask bit -> same selects).
// History: R1-R4 43-47us (same-line atomics), R5 scatter slots ->~29us,
// R6 row-per-patch DPP structure, R7 coalesced mapping (neutral).
// Harness overhead (256MB d_ws repoison ~40us + restores ~60us) is fixed
// and not addressable from the kernel.

#define WPB 4        // waves per 256-thread block
#define PPW 4        // patches per wave (one per DPP row)
#define NSLOTS 64    // scatter slots, each on its own 128-B cache line
#define MAXBLK 2048

// Full-wave sum -> wave-uniform scalar (DPP row_shr + row_bcast + readlane).
__device__ __forceinline__ float wredu(float v) {
#define DPP_ADD(ctrl)                                                        \
  v += __int_as_float(__builtin_amdgcn_update_dpp(                           \
      0, __float_as_int(v), (ctrl), 0xf, 0xf, true))
  DPP_ADD(0x111);  // row_shr:1
  DPP_ADD(0x112);  // row_shr:2
  DPP_ADD(0x114);  // row_shr:4
  DPP_ADD(0x118);  // row_shr:8
  DPP_ADD(0x142);  // row_bcast:15
  DPP_ADD(0x143);  // row_bcast:31
#undef DPP_ADD
  return __int_as_float(__builtin_amdgcn_readlane(__float_as_int(v), 63));
}

// Sum across the 16 lanes of each DPP row; EVERY lane of the row ends with
// the row total (rotation-add is a circulant reduction: spans 2,4,8,16).
__device__ __forceinline__ float rowredu(float v) {
#define DPP_ADD(ctrl)                                                        \
  v += __int_as_float(__builtin_amdgcn_update_dpp(                           \
      0, __float_as_int(v), (ctrl), 0xf, 0xf, true))
  DPP_ADD(0x121);  // row_ror:1
  DPP_ADD(0x122);  // row_ror:2
  DPP_ADD(0x124);  // row_ror:4
  DPP_ADD(0x128);  // row_ror:8
#undef DPP_ADD
  return v;
}

__device__ __forceinline__ float frcp(float x) {
  return __builtin_amdgcn_rcpf(x);   // ~1 ulp, 1 VALU instr
}

__global__ __launch_bounds__(256, 8) void moge_patch_kernel(
    const float* __restrict__ xg,   // pred_depth (B*N)
    const float* __restrict__ yg,   // gt_depth   (B*N)
    const int*   __restrict__ mg,   // mask       (B*N), 0/1
    const float* __restrict__ gsg,  // global_scale (B)
    const int*   __restrict__ pP,   // num_patches (device scalar)
    const int*   __restrict__ pK,   // patch_pixel_count (device scalar)
    int B,
    float* __restrict__ ws) {       // NSLOTS lines: [slot*32]=loss,[+1]=cnt
  const int P = pP[0];
  const int K = pK[0];
  const int lane = threadIdx.x & 63;
  const int wib  = threadIdx.x >> 6;
  const int total_patches = B * P;
  const float invK = 1.0f / (float)K;

  float wloss = 0.f, wcnt = 0.f;    // per-lane accumulators

  if (K == 256) {
    // ------- fast path: patch-per-row, 16 pixels/lane -----------------
    const int row = lane >> 4;       // 0..3 -> patch within wave
    const int col = lane & 15;       // lane within row
    const int wave_stride = gridDim.x * WPB * PPW;

    for (int pbase = (blockIdx.x * WPB + wib) * PPW; pbase < total_patches;
         pbase += wave_stride) {
      const int patch = pbase + row;
      const bool row_ok = patch < total_patches;
      // Coalesced mapping (R7): lane owns pixels {j*64 + col*4 + q}; load j
      // is a float4 at byte offset patch*1024 + j*256 + col*16 -> each
      // row's 16 lanes read a CONTIGUOUS 256 B per instruction.
      const long base = (row_ok ? (long)patch * 256L : 0L) + col * 4;

      float4 xa[4], ya[4];
      unsigned mb = 0;               // 16 mask bits, one per owned pixel
      {
        int4 ma[4];
        #pragma unroll
        for (int j = 0; j < 4; ++j) {
          ma[j] = *(const int4*)(mg + base + 64 * j);
          xa[j] = *(const float4*)(xg + base + 64 * j);
          ya[j] = *(const float4*)(yg + base + 64 * j);
        }
        const int* mi = (const int*)ma;
        #pragma unroll
        for (int i = 0; i < 16; ++i) mb |= (mi[i] ? 1u : 0u) << i;
      }                              // ma regs die here: peak live ~60 VGPR
      const float* xr = (const float*)xa;
      const float* yr = (const float*)ya;

      // -- pass 1: WLS sums (msum/symsum reduced alongside) ------------
      float sw = 0.f, swx = 0.f, swy = 0.f, swxx = 0.f, swxy = 0.f;
      float msum = 0.f, symsum = 0.f;
      #pragma unroll
      for (int i = 0; i < 16; ++i) {
        const bool on = (mb >> i) & 1u;
        const float m = on ? 1.f : 0.f;
        const float xx = xr[i], yy = yr[i];
        const float w = on ? frcp(fmaxf(yy, 1e-5f)) : 0.f;
        const float wx = w * xx;
        sw += w; swx += wx; swy = fmaf(w, yy, swy);
        swxx = fmaf(wx, xx, swxx); swxy = fmaf(wx, yy, swxy);
        msum += m; symsum = fmaf(m, yy, symsum);
      }
      sw = rowredu(sw); swx = rowredu(swx); swy = rowredu(swy);
      swxx = rowredu(swxx); swxy = rowredu(swxy);

      float det = sw * swxx - swx * swx;
      if (fabsf(det) < 1e-12f) det = 1e-12f;  // jnp.where -> +1e-12 any sign
      float rdet = frcp(det);
      const float s0 = (sw * swxy - swx * swy) * rdet;
      const float t0 = (swxx * swy - swx * swxy) * rdet;

      // -- pass 2: truncated refit (w recomputed, bit-identical) -------
      float sw2 = 0.f, swx2 = 0.f, swy2 = 0.f, swxx2 = 0.f, swxy2 = 0.f;
      #pragma unroll
      for (int i = 0; i < 16; ++i) {
        const float xx = xr[i], yy = yr[i];
        const float w = ((mb >> i) & 1u) ? frcp(fmaxf(yy, 1e-5f)) : 0.f;
        const float e = w * fabsf(fmaf(s0, xx, t0) - yy);
        const float w2 = (e < 1.0f) ? w : 0.f;  // TRUNC = 1.0, strict <
        const float w2x = w2 * xx;
        sw2 += w2; swx2 += w2x; swy2 = fmaf(w2, yy, swy2);
        swxx2 = fmaf(w2x, xx, swxx2); swxy2 = fmaf(w2x, yy, swxy2);
      }
      sw2 = rowredu(sw2); swx2 = rowredu(swx2); swy2 = rowredu(swy2);
      swxx2 = rowredu(swxx2); swxy2 = rowredu(swxy2);
      msum = rowredu(msum); symsum = rowredu(symsum);

      if (sw2 > 1e-8f) {  // sum(w2)==sw2; else fall back to pass-1 sums
        sw = sw2; swx = swx2; swy = swy2; swxx = swxx2; swxy = swxy2;
      }
      det = sw * swxx - swx * swx;
      if (fabsf(det) < 1e-12f) det = 1e-12f;
      rdet = frcp(det);
      const float s = (sw * swxy - swx * swy) * rdet;
      const float t = (swxx * swy - swx * swxy) * rdet;

      // -- pass 3: smooth-L1 patch loss --------------------------------
      const float mean_depth =
          (msum > 0.f) ? (symsum * frcp(fmaxf(msum, 1.f))) : 1.f;
      const float yfloor = 0.1f * mean_depth;

      float lsum = 0.f;
      #pragma unroll
      for (int i = 0; i < 16; ++i) {
        const float yy = yr[i];
        const float pw = ((mb >> i) & 1u) ? frcp(fmaxf(yy, yfloor)) : 0.f;
        const float err = fabsf(fmaf(s, xr[i], t) - yy) * pw;
        // BETA = 0.1: err<0.1 ? 0.5*err^2/0.1 : err-0.05
        lsum += (err < 0.1f) ? (5.0f * err * err) : (err - 0.05f);
      }
      const float patch_loss = rowredu(lsum) * invK;

      // -- validity (row-uniform), accumulate on col==0 ---------------
      const int pidx = row_ok ? patch : (total_patches - 1);
      const float gs = gsg[(unsigned)pidx / (unsigned)P];
      const float ratio = s * frcp(fmaxf(gs, 1e-12f));
      const bool gs_ok = (gs > 0.f) ? (ratio >= 0.1f && ratio <= 10.0f) : true;
      const bool valid = (msum * invK >= 0.3f) && (s > 0.f) && gs_ok;

      if (col == 0 && row_ok && valid) { wloss += patch_loss; wcnt += 1.f; }
    }
  } else {
    // ------- generic path (any K): wave-per-patch ---------------------
    const int wave_stride = gridDim.x * WPB;
    for (int patch = blockIdx.x * WPB + wib; patch < total_patches;
         patch += wave_stride) {
      const long base = (long)patch * (long)K;
      const float* xp = xg + base;
      const float* yp = yg + base;
      const int*   mp = mg + base;

      float sw = 0.f, swx = 0.f, swy = 0.f, swxx = 0.f, swxy = 0.f;
      float msum = 0.f, symsum = 0.f;
      for (int j = lane; j < K; j += 64) {
        const float m = mp[j] ? 1.f : 0.f;
        const float xx = xp[j], yy = yp[j];
        const float w = m * frcp(fmaxf(yy, 1e-5f));
        const float wx = w * xx;
        sw += w; swx += wx; swy = fmaf(w, yy, swy);
        swxx = fmaf(wx, xx, swxx); swxy = fmaf(wx, yy, swxy);
        msum += m; symsum = fmaf(m, yy, symsum);
      }
      sw = wredu(sw); swx = wredu(swx); swy = wredu(swy);
      swxx = wredu(swxx); swxy = wredu(swxy);
      msum = wredu(msum); symsum = wredu(symsum);

      float det = sw * swxx - swx * swx;
      if (fabsf(det) < 1e-12f) det = 1e-12f;
      float rdet = frcp(det);
      const float s0 = (sw * swxy - swx * swy) * rdet;
      const float t0 = (swxx * swy - swx * swxy) * rdet;

      float sw2 = 0.f, swx2 = 0.f, swy2 = 0.f, swxx2 = 0.f, swxy2 = 0.f;
      for (int j = lane; j < K; j += 64) {
        const float m = mp[j] ? 1.f : 0.f;
        const float xx = xp[j], yy = yp[j];
        const float w = m * frcp(fmaxf(yy, 1e-5f));
        const float e = w * fabsf(fmaf(s0, xx, t0) - yy);
        const float w2 = (e < 1.0f) ? w : 0.f;
        const float w2x = w2 * xx;
        sw2 += w2; swx2 += w2x; swy2 = fmaf(w2, yy, swy2);
        swxx2 = fmaf(w2x, xx, swxx2); swxy2 = fmaf(w2x, yy, swxy2);
      }
      sw2 = wredu(sw2); swx2 = wredu(swx2); swy2 = wredu(swy2);
      swxx2 = wredu(swxx2); swxy2 = wredu(swxy2);

      if (sw2 > 1e-8f) {
        sw = sw2; swx = swx2; swy = swy2; swxx = swxx2; swxy = swxy2;
      }
      det = sw * swxx - swx * swx;
      if (fabsf(det) < 1e-12f) det = 1e-12f;
      rdet = frcp(det);
      const float s = (sw * swxy - swx * swy) * rdet;
      const float t = (swxx * swy - swx * swxy) * rdet;

      const float mean_depth =
          (msum > 0.f) ? (symsum * frcp(fmaxf(msum, 1.f))) : 1.f;
      const float yfloor = 0.1f * mean_depth;

      float lsum = 0.f;
      for (int j = lane; j < K; j += 64) {
        const float m = mp[j] ? 1.f : 0.f;
        const float xx = xp[j], yy = yp[j];
        const float pw = m * frcp(fmaxf(yy, yfloor));
        const float err = fabsf(fmaf(s, xx, t) - yy) * pw;
        lsum += (err < 0.1f) ? (5.0f * err * err) : (err - 0.05f);
      }
      const float patch_loss = wredu(lsum) * invK;

      const float gs = gsg[(unsigned)patch / (unsigned)P];
      const float ratio = s * frcp(fmaxf(gs, 1e-12f));
      const bool gs_ok = (gs > 0.f) ? (ratio >= 0.1f && ratio <= 10.0f) : true;
      const bool valid = (msum * invK >= 0.3f) && (s > 0.f) && gs_ok;

      if (lane == 0 && valid) { wloss += patch_loss; wcnt += 1.f; }
    }
  }

  // ---- wave reduce -> block reduce (LDS) -> 2 atomics per block ------
  wloss = wredu(wloss);
  wcnt  = wredu(wcnt);
  __shared__ float sl[WPB], sc[WPB];
  if (lane == 0) { sl[wib] = wloss; sc[wib] = wcnt; }
  __syncthreads();
  if (threadIdx.x == 0) {
    float bl = 0.f, bc = 0.f;
    #pragma unroll
    for (int i = 0; i < WPB; ++i) { bl += sl[i]; bc += sc[i]; }
    const int slot = (blockIdx.x & (NSLOTS - 1)) * 32;  // own 128-B line
    atomicAdd(&ws[slot], bl);
    atomicAdd(&ws[slot + 1], bc);
  }
}

__global__ void finalize_kernel(const float* __restrict__ ws,
                                float* __restrict__ out) {
  const int t = threadIdx.x;  // 64 threads
  float l = wredu(ws[t * 32]);
  float c = wredu(ws[t * 32 + 1]);
  if (t == 0) out[0] = (c > 0.f) ? (l / fmaxf(c, 1.f)) : 0.f;
}

extern "C" void kernel_launch(void* const* d_in, const int* in_sizes, int n_in,
                              void* d_out, int out_size, void* d_ws, size_t ws_size,
                              hipStream_t stream) {
  const float* pred = (const float*)d_in[0];
  const float* gt   = (const float*)d_in[1];
  const int*   mask = (const int*)d_in[2];
  const float* gs   = (const float*)d_in[3];
  const int*   pP   = (const int*)d_in[4];
  const int*   pK   = (const int*)d_in[5];
  const int B = in_sizes[3];
  const long total_pixels = (long)in_sizes[0];
  float* ws = (float*)d_ws;

  // 64 slot-lines zeroed by a memset node (8 KB)
  hipMemsetAsync(ws, 0, NSLOTS * 32 * sizeof(float), stream);

  // grid sized for K=256: 16 patches per block (4 waves x 4 rows)
  long est_patches = total_pixels / 256;
  long blocks = (est_patches + WPB * PPW - 1) / (WPB * PPW);
  if (blocks < 1) blocks = 1;
  if (blocks > MAXBLK) blocks = MAXBLK;
  moge_patch_kernel<<<(int)blocks, 256, 0, stream>>>(pred, gt, mask, gs, pP,
                                                     pK, B, ws);
  finalize_kernel<<<1, 64, 0, stream>>>(ws, (float*)d_out);
}

// Round 3
// 127.337 us; speedup vs baseline: 1.4515x; 1.4515x over previous
//
#include <hip/hip_runtime.h>

// MoGeSampledLocalLoss: per-patch truncated robust affine depth alignment +
// smooth-L1 loss, global mean over valid patches.
//
// R9: revert R8's spill disaster + dual-group prefetch pipeline.
// R8 post-mortem: __launch_bounds__(256,8) clamped to 32 VGPRs -> 147 MB
// scratch WRITE_SIZE + 26 MB extra FETCH per dispatch, kernel 29->90us.
// But its counters proved the spill-free kernel is LATENCY-exposed (3.5
// TB/s effective vs 6.3 achievable, VALU ~13%): one iteration per wave
// (12 loads -> one exposed ~900cy wait -> compute -> exit) and two
// residency rounds (8192 waves, 4096 resident).
// R9: grid halved to 1024 blocks (single full-residency round); each wave
// processes TWO 4-patch groups, issuing all 24 loads before any compute.
// 24 outstanding loads/wave, group-B latency hides under group-A compute.
// Masks packed to 2x16 bits immediately (frees 32 VGPRs); peak live
// ~110 VGPR inside the 128 tier at __launch_bounds__(256,4).
// History: R1-R4 43-47us (same-line atomics), R5 scatter slots ->~29us,
// R6 row-per-patch DPP, R7 coalesced map (neutral), R8 occupancy=8 (SPILL,
// reverted). Harness overhead (256MB repoison ~41us + restores) fixed.

#define WPB 4        // waves per 256-thread block
#define PPW 4        // patches per wave-group (one per DPP row)
#define GPI 2        // groups per wave iteration (prefetch pair)
#define NSLOTS 64    // scatter slots, each on its own 128-B cache line
#define MAXBLK 2048

// Full-wave sum -> wave-uniform scalar (DPP row_shr + row_bcast + readlane).
__device__ __forceinline__ float wredu(float v) {
#define DPP_ADD(ctrl)                                                        \
  v += __int_as_float(__builtin_amdgcn_update_dpp(                           \
      0, __float_as_int(v), (ctrl), 0xf, 0xf, true))
  DPP_ADD(0x111);  // row_shr:1
  DPP_ADD(0x112);  // row_shr:2
  DPP_ADD(0x114);  // row_shr:4
  DPP_ADD(0x118);  // row_shr:8
  DPP_ADD(0x142);  // row_bcast:15
  DPP_ADD(0x143);  // row_bcast:31
#undef DPP_ADD
  return __int_as_float(__builtin_amdgcn_readlane(__float_as_int(v), 63));
}

// Sum across the 16 lanes of each DPP row; EVERY lane of the row ends with
// the row total (rotation-add is a circulant reduction: spans 2,4,8,16).
__device__ __forceinline__ float rowredu(float v) {
#define DPP_ADD(ctrl)                                                        \
  v += __int_as_float(__builtin_amdgcn_update_dpp(                           \
      0, __float_as_int(v), (ctrl), 0xf, 0xf, true))
  DPP_ADD(0x121);  // row_ror:1
  DPP_ADD(0x122);  // row_ror:2
  DPP_ADD(0x124);  // row_ror:4
  DPP_ADD(0x128);  // row_ror:8
#undef DPP_ADD
  return v;
}

__device__ __forceinline__ float frcp(float x) {
  return __builtin_amdgcn_rcpf(x);   // ~1 ulp, 1 VALU instr
}

// Solve + loss for one 4-patch group held in registers (16 px/lane).
// xr/yr: 16 floats in regs; mb: 16 mask bits; accumulates into wloss/wcnt.
__device__ __forceinline__ void process_group(
    const float* xr, const float* yr, unsigned mb, int patch, bool row_ok,
    int col, int P, int total_patches, const float* __restrict__ gsg,
    float invK, float& wloss, float& wcnt) {
  // -- pass 1: WLS sums (msum/symsum reduced alongside) ------------
  float sw = 0.f, swx = 0.f, swy = 0.f, swxx = 0.f, swxy = 0.f;
  float msum = 0.f, symsum = 0.f;
  #pragma unroll
  for (int i = 0; i < 16; ++i) {
    const bool on = (mb >> i) & 1u;
    const float m = on ? 1.f : 0.f;
    const float xx = xr[i], yy = yr[i];
    const float w = on ? frcp(fmaxf(yy, 1e-5f)) : 0.f;
    const float wx = w * xx;
    sw += w; swx += wx; swy = fmaf(w, yy, swy);
    swxx = fmaf(wx, xx, swxx); swxy = fmaf(wx, yy, swxy);
    msum += m; symsum = fmaf(m, yy, symsum);
  }
  sw = rowredu(sw); swx = rowredu(swx); swy = rowredu(swy);
  swxx = rowredu(swxx); swxy = rowredu(swxy);

  float det = sw * swxx - swx * swx;
  if (fabsf(det) < 1e-12f) det = 1e-12f;  // jnp.where -> +1e-12 any sign
  float rdet = frcp(det);
  const float s0 = (sw * swxy - swx * swy) * rdet;
  const float t0 = (swxx * swy - swx * swxy) * rdet;

  // -- pass 2: truncated refit (w recomputed, bit-identical) -------
  float sw2 = 0.f, swx2 = 0.f, swy2 = 0.f, swxx2 = 0.f, swxy2 = 0.f;
  #pragma unroll
  for (int i = 0; i < 16; ++i) {
    const float xx = xr[i], yy = yr[i];
    const float w = ((mb >> i) & 1u) ? frcp(fmaxf(yy, 1e-5f)) : 0.f;
    const float e = w * fabsf(fmaf(s0, xx, t0) - yy);
    const float w2 = (e < 1.0f) ? w : 0.f;  // TRUNC = 1.0, strict <
    const float w2x = w2 * xx;
    sw2 += w2; swx2 += w2x; swy2 = fmaf(w2, yy, swy2);
    swxx2 = fmaf(w2x, xx, swxx2); swxy2 = fmaf(w2x, yy, swxy2);
  }
  sw2 = rowredu(sw2); swx2 = rowredu(swx2); swy2 = rowredu(swy2);
  swxx2 = rowredu(swxx2); swxy2 = rowredu(swxy2);
  msum = rowredu(msum); symsum = rowredu(symsum);

  if (sw2 > 1e-8f) {  // sum(w2)==sw2; else fall back to pass-1 sums
    sw = sw2; swx = swx2; swy = swy2; swxx = swxx2; swxy = swxy2;
  }
  det = sw * swxx - swx * swx;
  if (fabsf(det) < 1e-12f) det = 1e-12f;
  rdet = frcp(det);
  const float s = (sw * swxy - swx * swy) * rdet;
  const float t = (swxx * swy - swx * swxy) * rdet;

  // -- pass 3: smooth-L1 patch loss --------------------------------
  const float mean_depth =
      (msum > 0.f) ? (symsum * frcp(fmaxf(msum, 1.f))) : 1.f;
  const float yfloor = 0.1f * mean_depth;

  float lsum = 0.f;
  #pragma unroll
  for (int i = 0; i < 16; ++i) {
    const float yy = yr[i];
    const float pw = ((mb >> i) & 1u) ? frcp(fmaxf(yy, yfloor)) : 0.f;
    const float err = fabsf(fmaf(s, xr[i], t) - yy) * pw;
    // BETA = 0.1: err<0.1 ? 0.5*err^2/0.1 : err-0.05
    lsum += (err < 0.1f) ? (5.0f * err * err) : (err - 0.05f);
  }
  const float patch_loss = rowredu(lsum) * invK;

  // -- validity (row-uniform), accumulate on col==0 ---------------
  const int pidx = row_ok ? patch : (total_patches - 1);
  const float gs = gsg[(unsigned)pidx / (unsigned)P];
  const float ratio = s * frcp(fmaxf(gs, 1e-12f));
  const bool gs_ok = (gs > 0.f) ? (ratio >= 0.1f && ratio <= 10.0f) : true;
  const bool valid = (msum * invK >= 0.3f) && (s > 0.f) && gs_ok;

  if (col == 0 && row_ok && valid) { wloss += patch_loss; wcnt += 1.f; }
}

__global__ __launch_bounds__(256, 4) void moge_patch_kernel(
    const float* __restrict__ xg,   // pred_depth (B*N)
    const float* __restrict__ yg,   // gt_depth   (B*N)
    const int*   __restrict__ mg,   // mask       (B*N), 0/1
    const float* __restrict__ gsg,  // global_scale (B)
    const int*   __restrict__ pP,   // num_patches (device scalar)
    const int*   __restrict__ pK,   // patch_pixel_count (device scalar)
    int B,
    float* __restrict__ ws) {       // NSLOTS lines: [slot*32]=loss,[+1]=cnt
  const int P = pP[0];
  const int K = pK[0];
  const int lane = threadIdx.x & 63;
  const int wib  = threadIdx.x >> 6;
  const int total_patches = B * P;
  const float invK = 1.0f / (float)K;

  float wloss = 0.f, wcnt = 0.f;    // per-lane accumulators

  if (K == 256) {
    // ------- fast path: patch-per-row, 16 pixels/lane, 2 groups -------
    const int row = lane >> 4;       // 0..3 -> patch within group
    const int col = lane & 15;       // lane within row
    const int wave_stride = gridDim.x * WPB * PPW * GPI;

    for (int pbase = (blockIdx.x * WPB + wib) * PPW * GPI;
         pbase < total_patches; pbase += wave_stride) {
      const int patchA = pbase + row;
      const int patchB = pbase + PPW + row;
      const bool okA = patchA < total_patches;
      const bool okB = patchB < total_patches;
      // Coalesced mapping (R7): lane owns pixels {j*64 + col*4 + q}; load j
      // is a float4 at byte offset patch*1024 + j*256 + col*16 -> each
      // row's 16 lanes read a CONTIGUOUS 256 B per instruction.
      const long baseA = (okA ? (long)patchA * 256L : 0L) + col * 4;
      const long baseB = (okB ? (long)patchB * 256L : 0L) + col * 4;

      // ---- issue ALL 24 loads for both groups before any compute ----
      float4 xa[4], ya[4], xb[4], yb[4];
      int4 maA[4], maB[4];
      #pragma unroll
      for (int j = 0; j < 4; ++j) {
        xa[j]  = *(const float4*)(xg + baseA + 64 * j);
        ya[j]  = *(const float4*)(yg + baseA + 64 * j);
        maA[j] = *(const int4*)(mg + baseA + 64 * j);
        xb[j]  = *(const float4*)(xg + baseB + 64 * j);
        yb[j]  = *(const float4*)(yg + baseB + 64 * j);
        maB[j] = *(const int4*)(mg + baseB + 64 * j);
      }
      unsigned mbA = 0, mbB = 0;     // pack masks -> frees 32 VGPRs
      {
        const int* miA = (const int*)maA;
        const int* miB = (const int*)maB;
        #pragma unroll
        for (int i = 0; i < 16; ++i) {
          mbA |= (miA[i] ? 1u : 0u) << i;
          mbB |= (miB[i] ? 1u : 0u) << i;
        }
      }

      process_group((const float*)xa, (const float*)ya, mbA, patchA, okA,
                    col, P, total_patches, gsg, invK, wloss, wcnt);
      process_group((const float*)xb, (const float*)yb, mbB, patchB, okB,
                    col, P, total_patches, gsg, invK, wloss, wcnt);
    }
  } else {
    // ------- generic path (any K): wave-per-patch ---------------------
    const int wave_stride = gridDim.x * WPB;
    for (int patch = blockIdx.x * WPB + wib; patch < total_patches;
         patch += wave_stride) {
      const long base = (long)patch * (long)K;
      const float* xp = xg + base;
      const float* yp = yg + base;
      const int*   mp = mg + base;

      float sw = 0.f, swx = 0.f, swy = 0.f, swxx = 0.f, swxy = 0.f;
      float msum = 0.f, symsum = 0.f;
      for (int j = lane; j < K; j += 64) {
        const float m = mp[j] ? 1.f : 0.f;
        const float xx = xp[j], yy = yp[j];
        const float w = m * frcp(fmaxf(yy, 1e-5f));
        const float wx = w * xx;
        sw += w; swx += wx; swy = fmaf(w, yy, swy);
        swxx = fmaf(wx, xx, swxx); swxy = fmaf(wx, yy, swxy);
        msum += m; symsum = fmaf(m, yy, symsum);
      }
      sw = wredu(sw); swx = wredu(swx); swy = wredu(swy);
      swxx = wredu(swxx); swxy = wredu(swxy);
      msum = wredu(msum); symsum = wredu(symsum);

      float det = sw * swxx - swx * swx;
      if (fabsf(det) < 1e-12f) det = 1e-12f;
      float rdet = frcp(det);
      const float s0 = (sw * swxy - swx * swy) * rdet;
      const float t0 = (swxx * swy - swx * swxy) * rdet;

      float sw2 = 0.f, swx2 = 0.f, swy2 = 0.f, swxx2 = 0.f, swxy2 = 0.f;
      for (int j = lane; j < K; j += 64) {
        const float m = mp[j] ? 1.f : 0.f;
        const float xx = xp[j], yy = yp[j];
        const float w = m * frcp(fmaxf(yy, 1e-5f));
        const float e = w * fabsf(fmaf(s0, xx, t0) - yy);
        const float w2 = (e < 1.0f) ? w : 0.f;
        const float w2x = w2 * xx;
        sw2 += w2; swx2 += w2x; swy2 = fmaf(w2, yy, swy2);
        swxx2 = fmaf(w2x, xx, swxx2); swxy2 = fmaf(w2x, yy, swxy2);
      }
      sw2 = wredu(sw2); swx2 = wredu(swx2); swy2 = wredu(swy2);
      swxx2 = wredu(swxx2); swxy2 = wredu(swxy2);

      if (sw2 > 1e-8f) {
        sw = sw2; swx = swx2; swy = swy2; swxx = swxx2; swxy = swxy2;
      }
      det = sw * swxx - swx * swx;
      if (fabsf(det) < 1e-12f) det = 1e-12f;
      rdet = frcp(det);
      const float s = (sw * swxy - swx * swy) * rdet;
      const float t = (swxx * swy - swx * swxy) * rdet;

      const float mean_depth =
          (msum > 0.f) ? (symsum * frcp(fmaxf(msum, 1.f))) : 1.f;
      const float yfloor = 0.1f * mean_depth;

      float lsum = 0.f;
      for (int j = lane; j < K; j += 64) {
        const float m = mp[j] ? 1.f : 0.f;
        const float xx = xp[j], yy = yp[j];
        const float pw = m * frcp(fmaxf(yy, yfloor));
        const float err = fabsf(fmaf(s, xx, t) - yy) * pw;
        lsum += (err < 0.1f) ? (5.0f * err * err) : (err - 0.05f);
      }
      const float patch_loss = wredu(lsum) * invK;

      const float gs = gsg[(unsigned)patch / (unsigned)P];
      const float ratio = s * frcp(fmaxf(gs, 1e-12f));
      const bool gs_ok = (gs > 0.f) ? (ratio >= 0.1f && ratio <= 10.0f) : true;
      const bool valid = (msum * invK >= 0.3f) && (s > 0.f) && gs_ok;

      if (lane == 0 && valid) { wloss += patch_loss; wcnt += 1.f; }
    }
  }

  // ---- wave reduce -> block reduce (LDS) -> 2 atomics per block ------
  wloss = wredu(wloss);
  wcnt  = wredu(wcnt);
  __shared__ float sl[WPB], sc[WPB];
  if (lane == 0) { sl[wib] = wloss; sc[wib] = wcnt; }
  __syncthreads();
  if (threadIdx.x == 0) {
    float bl = 0.f, bc = 0.f;
    #pragma unroll
    for (int i = 0; i < WPB; ++i) { bl += sl[i]; bc += sc[i]; }
    const int slot = (blockIdx.x & (NSLOTS - 1)) * 32;  // own 128-B line
    atomicAdd(&ws[slot], bl);
    atomicAdd(&ws[slot + 1], bc);
  }
}

__global__ void finalize_kernel(const float* __restrict__ ws,
                                float* __restrict__ out) {
  const int t = threadIdx.x;  // 64 threads
  float l = wredu(ws[t * 32]);
  float c = wredu(ws[t * 32 + 1]);
  if (t == 0) out[0] = (c > 0.f) ? (l / fmaxf(c, 1.f)) : 0.f;
}

extern "C" void kernel_launch(void* const* d_in, const int* in_sizes, int n_in,
                              void* d_out, int out_size, void* d_ws, size_t ws_size,
                              hipStream_t stream) {
  const float* pred = (const float*)d_in[0];
  const float* gt   = (const float*)d_in[1];
  const int*   mask = (const int*)d_in[2];
  const float* gs   = (const float*)d_in[3];
  const int*   pP   = (const int*)d_in[4];
  const int*   pK   = (const int*)d_in[5];
  const int B = in_sizes[3];
  const long total_pixels = (long)in_sizes[0];
  float* ws = (float*)d_ws;

  // 64 slot-lines zeroed by a memset node (8 KB)
  hipMemsetAsync(ws, 0, NSLOTS * 32 * sizeof(float), stream);

  // grid sized for K=256: 32 patches per block (4 waves x 4 rows x 2 grp)
  long est_patches = total_pixels / 256;
  long blocks = (est_patches + WPB * PPW * GPI - 1) / (WPB * PPW * GPI);
  if (blocks < 1) blocks = 1;
  if (blocks > MAXBLK) blocks = MAXBLK;
  moge_patch_kernel<<<(int)blocks, 256, 0, stream>>>(pred, gt, mask, gs, pP,
                                                     pK, B, ws);
  finalize_kernel<<<1, 64, 0, stream>>>(ws, (float*)d_out);
}